// Round 3
// baseline (1495.015 us; speedup 1.0000x reference)
//
#include <hip/hip_runtime.h>
#include <math.h>

#define TT 512
#define BB 512
#define CC 32
#define CIN 33
#define HH 128
#define GG 512
#define EPSF 1e-12f

typedef short short8 __attribute__((ext_vector_type(8)));
typedef short short4v __attribute__((ext_vector_type(4)));
typedef float f32x4 __attribute__((ext_vector_type(4)));

#define MFMA16(a, b, c) __builtin_amdgcn_mfma_f32_16x16x32_bf16(a, b, c, 0, 0, 0)

__device__ __forceinline__ unsigned short f2bf(float f) {
    unsigned u = __float_as_uint(f);
    unsigned r = (u + 0x7fffu + ((u >> 16) & 1u)) >> 16;
    return (unsigned short)r;
}
__device__ __forceinline__ float bf2f(unsigned short s) {
    return __uint_as_float(((unsigned)s) << 16);
}
__device__ __forceinline__ float fsig(float x) { return 1.f / (1.f + __expf(-x)); }
__device__ __forceinline__ float ftanh(float x) { return 1.f - 2.f / (1.f + __expf(2.f * x)); }

// ---------------------------------------------------------------------------
// Kernel 1: s[t] = mean_c std_b(x[:,t,c], ddof=1)   -> ws[0..511]
// ---------------------------------------------------------------------------
__global__ void std_kernel(const float* __restrict__ x, float* __restrict__ ws) {
    const int t = blockIdx.x;
    const int c = threadIdx.x & 31;
    const int sl = threadIdx.x >> 5;
    float sum = 0.f, sq = 0.f;
    for (int k = 0; k < 64; ++k) {
        const int b = sl * 64 + k;
        float v = x[((size_t)b * TT + t) * CC + c];
        sum += v;
        sq  = fmaf(v, v, sq);
    }
    __shared__ float rs[8][32];
    __shared__ float rq[8][32];
    rs[sl][c] = sum; rq[sl][c] = sq;
    __syncthreads();
    if (threadIdx.x < 32) {
        float S = 0.f, Q = 0.f;
        for (int i = 0; i < 8; ++i) { S += rs[i][threadIdx.x]; Q += rq[i][threadIdx.x]; }
        float mean = S / 512.0f;
        float var  = (Q - 512.0f * mean * mean) / 511.0f;
        rs[0][threadIdx.x] = sqrtf(fmaxf(var, 0.f));
    }
    __syncthreads();
    if (threadIdx.x == 0) {
        float m = 0.f;
        for (int i = 0; i < 32; ++i) m += rs[0][i];
        ws[t] = m / 32.0f;
    }
}

// ---------------------------------------------------------------------------
// Kernel 2: sigmas -> ws[512]=sig_ih, ws[513]=sig_hh, ws[514]=sig_fc
// ---------------------------------------------------------------------------
__global__ void sigma_kernel(const float* __restrict__ w_ih, const float* __restrict__ u_ih,
                             const float* __restrict__ w_hh, const float* __restrict__ u_hh,
                             const float* __restrict__ fc_w, const float* __restrict__ u_fc,
                             float* __restrict__ ws) {
    const int tid = threadIdx.x;
    __shared__ float red[512];
    __shared__ float vv[128];

    {   // sigma_hh
        const int c = tid & 127, q = tid >> 7;
        float part = 0.f;
        for (int g = q * 128; g < q * 128 + 128; ++g)
            part = fmaf(w_hh[g * HH + c], u_hh[g], part);
        red[tid] = part;
        __syncthreads();
        if (tid < 128) vv[tid] = red[tid] + red[tid + 128] + red[tid + 256] + red[tid + 384];
        __syncthreads();
        red[tid] = (tid < 128) ? vv[tid] * vv[tid] : 0.f;
        __syncthreads();
        for (int s = 64; s >= 1; s >>= 1) { if (tid < s) red[tid] += red[tid + s]; __syncthreads(); }
        const float nv = sqrtf(red[0]);
        __syncthreads();
        if (tid < 128) vv[tid] = vv[tid] / (nv + EPSF);
        __syncthreads();
        float wv = 0.f;
        for (int c2 = 0; c2 < 128; ++c2) wv = fmaf(w_hh[tid * HH + c2], vv[c2], wv);
        red[tid] = wv * wv;
        __syncthreads();
        for (int s = 256; s >= 1; s >>= 1) { if (tid < s) red[tid] += red[tid + s]; __syncthreads(); }
        if (tid == 0) { float ns2 = red[0]; ws[513] = ns2 / (sqrtf(ns2) + EPSF); }
        __syncthreads();
    }
    {   // sigma_ih
        float part = 0.f;
        if (tid < CIN) {
            for (int g = 0; g < 512; ++g) part = fmaf(w_ih[g * CIN + tid], u_ih[g], part);
            red[tid] = part;
        }
        __syncthreads();
        if (tid == 0) {
            float n2 = 0.f;
            for (int i = 0; i < CIN; ++i) n2 += red[i] * red[i];
            red[400] = sqrtf(n2);
        }
        __syncthreads();
        const float nv = red[400];
        if (tid < CIN) vv[tid] = red[tid] / (nv + EPSF);
        __syncthreads();
        float wv = 0.f;
        for (int c2 = 0; c2 < CIN; ++c2) wv = fmaf(w_ih[tid * CIN + c2], vv[c2], wv);
        red[tid] = wv * wv;
        __syncthreads();
        for (int s = 256; s >= 1; s >>= 1) { if (tid < s) red[tid] += red[tid + s]; __syncthreads(); }
        if (tid == 0) { float ns2 = red[0]; ws[512] = ns2 / (sqrtf(ns2) + EPSF); }
        __syncthreads();
    }
    {   // sigma_fc
        red[tid] = (tid < 128) ? fc_w[tid] * fc_w[tid] : 0.f;
        __syncthreads();
        for (int s = 64; s >= 1; s >>= 1) { if (tid < s) red[tid] += red[tid + s]; __syncthreads(); }
        if (tid == 0) {
            float nw2 = red[0];
            float u0  = u_fc[0];
            float nv  = fabsf(u0) * sqrtf(nw2);
            float wv  = u0 * nw2 / (nv + EPSF);
            ws[514]   = wv * wv / (fabsf(wv) + EPSF);
        }
    }
}

// ---------------------------------------------------------------------------
// Kernel 3: MFMA LSTM. 32 blocks x 16 batch rows, 512 threads (8 waves).
// __launch_bounds__(512,1): weights need 160 VGPRs stationary; (512,2)'s
// 128-VGPR cap spilled them to scratch (round-2: 6400 cyc/step). 1 block/CU
// is fine -- only 32 blocks exist, one per CU regardless.
// ---------------------------------------------------------------------------
__global__ __launch_bounds__(512, 1) void lstm_mfma(
    const float* __restrict__ x,
    const float* __restrict__ w_ih, const float* __restrict__ w_hh,
    const float* __restrict__ b_ih, const float* __restrict__ b_hh,
    const float* __restrict__ attn_w, const float* __restrict__ attn_b,
    const float* __restrict__ fc_w, const float* __restrict__ fc_b,
    const float* __restrict__ ws,
    float* __restrict__ out)
{
    const int tid = threadIdx.x;
    const int w   = tid >> 6;          // wave 0..7
    const int l   = tid & 63;          // lane
    const int m   = l & 15;            // A-row / B-col / D-col index
    const int q   = l >> 4;            // quad 0..3
    const int b0  = blockIdx.x * 16;
    const int jcol = 16 * w + m;       // this lane's h column

    const float rih = 1.f / ws[512];
    const float rhh = 1.f / ws[513];
    const float rfc = 1.f / ws[514];
    const float attb = attn_b[0];

    // LDS: double-buffered h planes (bf16 hi/lo), x planes, softmax scratch
    __shared__ __align__(16) short hsH[2][16][136];
    __shared__ __align__(16) short hsL[2][16][136];
    __shared__ __align__(16) short xsH[2][16][40];
    __shared__ __align__(16) short xsL[2][16][40];
    __shared__ float ab[2][16];
    __shared__ float Sf[16];

    // ---- stationary weights: B-frags BH/BL[p][kt], p=gate-type, kt=K-tile ----
    short8 BH[4][5], BL[4][5];
    float biasg[4], w32g[4];
#pragma unroll
    for (int p = 0; p < 4; ++p) {
        const int g = 16 * w + 128 * p + m;
        float tmp[8];
#pragma unroll
        for (int kt = 0; kt < 4; ++kt) {
            const float* src = w_hh + (size_t)g * HH + kt * 32 + q * 8;
#pragma unroll
            for (int i = 0; i < 8; ++i) tmp[i] = src[i] * rhh;
#pragma unroll
            for (int i = 0; i < 8; ++i) {
                unsigned short h = f2bf(tmp[i]);
                BH[p][kt][i] = (short)h;
                BL[p][kt][i] = (short)f2bf(tmp[i] - bf2f(h));
            }
        }
        {
            const float* src = w_ih + (size_t)g * CIN + q * 8;
#pragma unroll
            for (int i = 0; i < 8; ++i) tmp[i] = src[i] * rih;
#pragma unroll
            for (int i = 0; i < 8; ++i) {
                unsigned short h = f2bf(tmp[i]);
                BH[p][4][i] = (short)h;
                BL[p][4][i] = (short)f2bf(tmp[i] - bf2f(h));
            }
        }
        w32g[p]  = w_ih[(size_t)g * CIN + 32] * rih;
        biasg[p] = b_ih[g] + b_hh[g];
    }
    const float fcwj = fc_w[jcol] * rfc;

    // attention-dot constants for logit phase (lane role: row rrow, chunk kc)
    const int rrow = 2 * w + (l >> 5);
    const int kc   = l & 31;
    float aw[4];
#pragma unroll
    for (int i = 0; i < 4; ++i) aw[i] = attn_w[kc * 4 + i];

    // zero h_{-1} (buffer 1)
    for (int i = tid; i < 16 * 136; i += 512) { hsH[1][0][i] = 0; hsL[1][0][i] = 0; }
    // stage x for t=0 into buffer 0
    if (tid < 128) {
        const int r = tid >> 3, c4 = tid & 7;
        float4 xv = *reinterpret_cast<const float4*>(x + ((size_t)(b0 + r) * TT + 0) * CC + c4 * 4);
        short4v hi, lo;
        float v[4] = {xv.x, xv.y, xv.z, xv.w};
#pragma unroll
        for (int i = 0; i < 4; ++i) {
            unsigned short h = f2bf(v[i]);
            hi[i] = (short)h; lo[i] = (short)f2bf(v[i] - bf2f(h));
        }
        *(short4v*)&xsH[0][r][c4 * 4] = hi;
        *(short4v*)&xsL[0][r][c4 * 4] = lo;
    }

    float c_st[4] = {0.f, 0.f, 0.f, 0.f};
    float P[4]    = {0.f, 0.f, 0.f, 0.f};
    float hprev[4] = {0.f, 0.f, 0.f, 0.f};
    float mreg = -INFINITY, Sreg = 0.f;
    __syncthreads();

    for (int t = 0; t < TT; ++t) {
        const int hr = (t + 1) & 1;    // buffer holding h_{t-1}
        const int hw = t & 1;          // buffer to write h_t
        const float s_t = ws[t];

        // prefetch next x (global)
        float4 xv;
        const int xr = tid >> 3, xc4 = tid & 7;
        if (tid < 128 && t + 1 < TT)
            xv = *reinterpret_cast<const float4*>(x + ((size_t)(b0 + xr) * TT + (t + 1)) * CC + xc4 * 4);

        // ---- logits for h_{t-1} (all waves, 2 rows each) ----
        if (t > 0) {
            float acc = 0.f;
            short4v hh = *(const short4v*)&hsH[hr][rrow][kc * 4];
            short4v ll = *(const short4v*)&hsL[hr][rrow][kc * 4];
#pragma unroll
            for (int i = 0; i < 4; ++i) {
                float hv = bf2f((unsigned short)hh[i]) + bf2f((unsigned short)ll[i]);
                acc = fmaf(aw[i], hv, acc);
            }
#pragma unroll
            for (int off = 1; off < 32; off <<= 1) acc += __shfl_xor(acc, off, 64);
            float logit = acc + attb;
            float mn = fmaxf(mreg, logit);
            float alpha = __expf(mreg - mn);
            float beta  = __expf(logit - mn);
            Sreg = Sreg * alpha + beta;
            mreg = mn;
            if (kc == 0) { ab[0][rrow] = alpha; ab[1][rrow] = beta; }
        }

        // ---- C init + MFMA ----
        f32x4 acc0, acc1, acc2, acc3;
        {
            float c0 = fmaf(w32g[0], s_t, biasg[0]);
            float c1 = fmaf(w32g[1], s_t, biasg[1]);
            float c2 = fmaf(w32g[2], s_t, biasg[2]);
            float c3 = fmaf(w32g[3], s_t, biasg[3]);
            acc0 = (f32x4){c0, c0, c0, c0};
            acc1 = (f32x4){c1, c1, c1, c1};
            acc2 = (f32x4){c2, c2, c2, c2};
            acc3 = (f32x4){c3, c3, c3, c3};
        }
#pragma unroll
        for (int kt = 0; kt < 5; ++kt) {
            short8 ah, al;
            if (kt < 4) {
                ah = *(const short8*)&hsH[hr][m][kt * 32 + q * 8];
                al = *(const short8*)&hsL[hr][m][kt * 32 + q * 8];
            } else {
                ah = *(const short8*)&xsH[t & 1][m][q * 8];
                al = *(const short8*)&xsL[t & 1][m][q * 8];
            }
            acc0 = MFMA16(ah, BH[0][kt], acc0);
            acc1 = MFMA16(ah, BH[1][kt], acc1);
            acc2 = MFMA16(ah, BH[2][kt], acc2);
            acc3 = MFMA16(ah, BH[3][kt], acc3);
            acc0 = MFMA16(al, BH[0][kt], acc0);
            acc1 = MFMA16(al, BH[1][kt], acc1);
            acc2 = MFMA16(al, BH[2][kt], acc2);
            acc3 = MFMA16(al, BH[3][kt], acc3);
            acc0 = MFMA16(ah, BL[0][kt], acc0);
            acc1 = MFMA16(ah, BL[1][kt], acc1);
            acc2 = MFMA16(ah, BL[2][kt], acc2);
            acc3 = MFMA16(ah, BL[3][kt], acc3);
        }

        __syncthreads();   // S1: ab visible; all A-reads of hr done

        // stage x_{t+1} into buffer (t+1)&1
        if (tid < 128 && t + 1 < TT) {
            short4v hi, lo;
            float v[4] = {xv.x, xv.y, xv.z, xv.w};
#pragma unroll
            for (int i = 0; i < 4; ++i) {
                unsigned short h = f2bf(v[i]);
                hi[i] = (short)h; lo[i] = (short)f2bf(v[i] - bf2f(h));
            }
            *(short4v*)&xsH[(t + 1) & 1][xr][xc4 * 4] = hi;
            *(short4v*)&xsL[(t + 1) & 1][xr][xc4 * 4] = lo;
        }

        // ---- P update with alpha/beta of step t-1 ----
        if (t > 0) {
#pragma unroll
            for (int i = 0; i < 4; ++i) {
                const int r_i = q * 4 + i;
                P[i] = fmaf(P[i], ab[0][r_i], ab[1][r_i] * hprev[i]);
            }
        }

        // ---- activations + state update (rows q*4+i, column jcol) ----
#pragma unroll
        for (int i = 0; i < 4; ++i) {
            float ig = fsig(acc0[i]);
            float fg = fsig(acc1[i]);
            float gg = ftanh(acc2[i]);
            float og = fsig(acc3[i]);
            c_st[i] = fmaf(fg, c_st[i], ig * gg);
            float hv = og * ftanh(c_st[i]);
            hprev[i] = hv;
            unsigned short hh = f2bf(hv);
            const int r_i = q * 4 + i;
            hsH[hw][r_i][jcol] = (short)hh;
            hsL[hw][r_i][jcol] = (short)f2bf(hv - bf2f(hh));
        }

        __syncthreads();   // S3: h_t + x_{t+1} visible
    }

    // ---- epilogue: logit for h_511, final P update, FC projection ----
    {
        float acc = 0.f;
        short4v hh = *(const short4v*)&hsH[1][rrow][kc * 4];
        short4v ll = *(const short4v*)&hsL[1][rrow][kc * 4];
#pragma unroll
        for (int i = 0; i < 4; ++i) {
            float hv = bf2f((unsigned short)hh[i]) + bf2f((unsigned short)ll[i]);
            acc = fmaf(aw[i], hv, acc);
        }
#pragma unroll
        for (int off = 1; off < 32; off <<= 1) acc += __shfl_xor(acc, off, 64);
        float logit = acc + attb;
        float mn = fmaxf(mreg, logit);
        float alpha = __expf(mreg - mn);
        float beta  = __expf(logit - mn);
        Sreg = Sreg * alpha + beta;
        if (kc == 0) { ab[0][rrow] = alpha; ab[1][rrow] = beta; Sf[rrow] = Sreg; }
    }
    __syncthreads();
    float* sc = (float*)&hsH[0][0][0];   // reuse as [16][132] fp32 scratch
#pragma unroll
    for (int i = 0; i < 4; ++i) {
        const int r_i = q * 4 + i;
        float Pv = fmaf(P[i], ab[0][r_i], ab[1][r_i] * hprev[i]);
        sc[r_i * 132 + jcol] = (Pv / Sf[r_i]) * fcwj;
    }
    __syncthreads();
    {
        float acc2 = 0.f;
#pragma unroll
        for (int i = 0; i < 4; ++i) acc2 += sc[rrow * 132 + kc * 4 + i];
#pragma unroll
        for (int off = 1; off < 32; off <<= 1) acc2 += __shfl_xor(acc2, off, 64);
        if (kc == 0) out[b0 + rrow] = acc2 + fc_b[0];
    }
}

// ---------------------------------------------------------------------------
extern "C" void kernel_launch(void* const* d_in, const int* in_sizes, int n_in,
                              void* d_out, int out_size, void* d_ws, size_t ws_size,
                              hipStream_t stream) {
    const float* x      = (const float*)d_in[0];
    const float* w_ih   = (const float*)d_in[1];
    const float* u_ih   = (const float*)d_in[2];
    const float* w_hh   = (const float*)d_in[3];
    const float* u_hh   = (const float*)d_in[4];
    const float* b_ih   = (const float*)d_in[5];
    const float* b_hh   = (const float*)d_in[6];
    const float* attn_w = (const float*)d_in[7];
    const float* attn_b = (const float*)d_in[8];
    const float* fc_w   = (const float*)d_in[9];
    const float* u_fc   = (const float*)d_in[10];
    const float* fc_b   = (const float*)d_in[11];
    float* ws  = (float*)d_ws;
    float* out = (float*)d_out;

    std_kernel<<<TT, 256, 0, stream>>>(x, ws);
    sigma_kernel<<<1, 512, 0, stream>>>(w_ih, u_ih, w_hh, u_hh, fc_w, u_fc, ws);
    lstm_mfma<<<BB / 16, 512, 0, stream>>>(x, w_ih, w_hh, b_ih, b_hh,
                                           attn_w, attn_b, fc_w, fc_b, ws, out);
}

// Round 4
// 1126.474 us; speedup vs baseline: 1.3272x; 1.3272x over previous
//
#include <hip/hip_runtime.h>
#include <math.h>

#define TT 512
#define BB 512
#define CC 32
#define CIN 33
#define HH 128
#define GG 512
#define EPSF 1e-12f

typedef _Float16 half8 __attribute__((ext_vector_type(8)));
typedef _Float16 half4 __attribute__((ext_vector_type(4)));
typedef float f32x4 __attribute__((ext_vector_type(4)));

#define MFMA16H(a, b, c) __builtin_amdgcn_mfma_f32_16x16x32_f16(a, b, c, 0, 0, 0)

__device__ __forceinline__ float fsig(float x) { return 1.f / (1.f + __expf(-x)); }
__device__ __forceinline__ float ftanh(float x) { return 1.f - 2.f / (1.f + __expf(2.f * x)); }

// ---------------------------------------------------------------------------
// Kernel 1: s[t] = mean_c std_b(x[:,t,c], ddof=1)   -> ws[0..511]
// ---------------------------------------------------------------------------
__global__ void std_kernel(const float* __restrict__ x, float* __restrict__ ws) {
    const int t = blockIdx.x;
    const int c = threadIdx.x & 31;
    const int sl = threadIdx.x >> 5;
    float sum = 0.f, sq = 0.f;
    for (int k = 0; k < 64; ++k) {
        const int b = sl * 64 + k;
        float v = x[((size_t)b * TT + t) * CC + c];
        sum += v;
        sq  = fmaf(v, v, sq);
    }
    __shared__ float rs[8][32];
    __shared__ float rq[8][32];
    rs[sl][c] = sum; rq[sl][c] = sq;
    __syncthreads();
    if (threadIdx.x < 32) {
        float S = 0.f, Q = 0.f;
        for (int i = 0; i < 8; ++i) { S += rs[i][threadIdx.x]; Q += rq[i][threadIdx.x]; }
        float mean = S / 512.0f;
        float var  = (Q - 512.0f * mean * mean) / 511.0f;
        rs[0][threadIdx.x] = sqrtf(fmaxf(var, 0.f));
    }
    __syncthreads();
    if (threadIdx.x == 0) {
        float m = 0.f;
        for (int i = 0; i < 32; ++i) m += rs[0][i];
        ws[t] = m / 32.0f;
    }
}

// ---------------------------------------------------------------------------
// Kernel 2: sigmas -> ws[512]=sig_ih, ws[513]=sig_hh, ws[514]=sig_fc
// ---------------------------------------------------------------------------
__global__ void sigma_kernel(const float* __restrict__ w_ih, const float* __restrict__ u_ih,
                             const float* __restrict__ w_hh, const float* __restrict__ u_hh,
                             const float* __restrict__ fc_w, const float* __restrict__ u_fc,
                             float* __restrict__ ws) {
    const int tid = threadIdx.x;
    __shared__ float red[512];
    __shared__ float vv[128];

    {   // sigma_hh
        const int c = tid & 127, q = tid >> 7;
        float part = 0.f;
        for (int g = q * 128; g < q * 128 + 128; ++g)
            part = fmaf(w_hh[g * HH + c], u_hh[g], part);
        red[tid] = part;
        __syncthreads();
        if (tid < 128) vv[tid] = red[tid] + red[tid + 128] + red[tid + 256] + red[tid + 384];
        __syncthreads();
        red[tid] = (tid < 128) ? vv[tid] * vv[tid] : 0.f;
        __syncthreads();
        for (int s = 64; s >= 1; s >>= 1) { if (tid < s) red[tid] += red[tid + s]; __syncthreads(); }
        const float nv = sqrtf(red[0]);
        __syncthreads();
        if (tid < 128) vv[tid] = vv[tid] / (nv + EPSF);
        __syncthreads();
        float wv = 0.f;
        for (int c2 = 0; c2 < 128; ++c2) wv = fmaf(w_hh[tid * HH + c2], vv[c2], wv);
        red[tid] = wv * wv;
        __syncthreads();
        for (int s = 256; s >= 1; s >>= 1) { if (tid < s) red[tid] += red[tid + s]; __syncthreads(); }
        if (tid == 0) { float ns2 = red[0]; ws[513] = ns2 / (sqrtf(ns2) + EPSF); }
        __syncthreads();
    }
    {   // sigma_ih
        float part = 0.f;
        if (tid < CIN) {
            for (int g = 0; g < 512; ++g) part = fmaf(w_ih[g * CIN + tid], u_ih[g], part);
            red[tid] = part;
        }
        __syncthreads();
        if (tid == 0) {
            float n2 = 0.f;
            for (int i = 0; i < CIN; ++i) n2 += red[i] * red[i];
            red[400] = sqrtf(n2);
        }
        __syncthreads();
        const float nv = red[400];
        if (tid < CIN) vv[tid] = red[tid] / (nv + EPSF);
        __syncthreads();
        float wv = 0.f;
        for (int c2 = 0; c2 < CIN; ++c2) wv = fmaf(w_ih[tid * CIN + c2], vv[c2], wv);
        red[tid] = wv * wv;
        __syncthreads();
        for (int s = 256; s >= 1; s >>= 1) { if (tid < s) red[tid] += red[tid + s]; __syncthreads(); }
        if (tid == 0) { float ns2 = red[0]; ws[512] = ns2 / (sqrtf(ns2) + EPSF); }
        __syncthreads();
    }
    {   // sigma_fc
        red[tid] = (tid < 128) ? fc_w[tid] * fc_w[tid] : 0.f;
        __syncthreads();
        for (int s = 64; s >= 1; s >>= 1) { if (tid < s) red[tid] += red[tid + s]; __syncthreads(); }
        if (tid == 0) {
            float nw2 = red[0];
            float u0  = u_fc[0];
            float nv  = fabsf(u0) * sqrtf(nw2);
            float wv  = u0 * nw2 / (nv + EPSF);
            ws[514]   = wv * wv / (fabsf(wv) + EPSF);
        }
    }
}

// ---------------------------------------------------------------------------
// Kernel 3: fp16 single-term MFMA LSTM. 32 blocks x 16 batch rows, 8 waves.
// Weights fp16 in 80 VGPRs, pinned with asm so the allocator can't remat the
// conversion in-loop (round-3 lesson: remat VALU was 60% of the step).
// One barrier per step (double-buffered h/x/ab, P-update delayed one step).
// ---------------------------------------------------------------------------
__global__ __attribute__((amdgpu_flat_work_group_size(512, 512), amdgpu_waves_per_eu(2, 2)))
void lstm_mfma(
    const float* __restrict__ x,
    const float* __restrict__ w_ih, const float* __restrict__ w_hh,
    const float* __restrict__ b_ih, const float* __restrict__ b_hh,
    const float* __restrict__ attn_w, const float* __restrict__ attn_b,
    const float* __restrict__ fc_w, const float* __restrict__ fc_b,
    const float* __restrict__ ws,
    float* __restrict__ out)
{
    const int tid = threadIdx.x;
    const int w   = tid >> 6;          // wave 0..7
    const int l   = tid & 63;          // lane
    const int m   = l & 15;            // A-row / B-col index
    const int q   = l >> 4;            // quad 0..3
    const int b0  = blockIdx.x * 16;
    const int jcol = 16 * w + m;       // this lane's h column

    const float rih = 1.f / ws[512];
    const float rhh = 1.f / ws[513];
    const float rfc = 1.f / ws[514];
    const float attb = attn_b[0];

    __shared__ __align__(16) _Float16 hs[2][16][136];   // h_t planes (fp16)
    __shared__ __align__(16) _Float16 xs[2][16][40];    // x_t planes (fp16)
    __shared__ float ab2[2][2][16];                     // [parity][alpha|beta][row]
    __shared__ float Sf[16];

    // ---- stationary fp16 weights: B-frags Bf[p][kt] ----
    half8 Bf[4][5];
    float biasg[4], w32g[4];
#pragma unroll
    for (int p = 0; p < 4; ++p) {
        const int g = 16 * w + 128 * p + m;
#pragma unroll
        for (int kt = 0; kt < 4; ++kt) {
            const float* src = w_hh + (size_t)g * HH + kt * 32 + q * 8;
#pragma unroll
            for (int i = 0; i < 8; ++i) Bf[p][kt][i] = (_Float16)(src[i] * rhh);
        }
        {
            const float* src = w_ih + (size_t)g * CIN + q * 8;
#pragma unroll
            for (int i = 0; i < 8; ++i) Bf[p][4][i] = (_Float16)(src[i] * rih);
        }
        w32g[p]  = w_ih[(size_t)g * CIN + 32] * rih;
        biasg[p] = b_ih[g] + b_hh[g];
    }
    // pin: forbid rematerialization of the conversion inside the loop
#pragma unroll
    for (int p = 0; p < 4; ++p) {
#pragma unroll
        for (int kt = 0; kt < 5; ++kt) asm volatile("" : "+v"(Bf[p][kt]));
        asm volatile("" : "+v"(biasg[p]), "+v"(w32g[p]));
    }
    const float fcwj = fc_w[jcol] * rfc;

    // logit-phase role: row rrow (2 rows/wave), K-chunk kc
    const int rrow = 2 * w + (l >> 5);
    const int kc   = l & 31;
    float aw[4];
#pragma unroll
    for (int i = 0; i < 4; ++i) aw[i] = attn_w[kc * 4 + i];

    // zero h_{-1} (buffer 1); stage x_0 into xs[0]
    for (int i = tid; i < 2 * 16 * 136; i += 512) (&hs[0][0][0])[i] = (_Float16)0.f;
    if (tid < 128) {
        const int r = tid >> 3, c4 = tid & 7;
        float4 xv = *reinterpret_cast<const float4*>(x + ((size_t)(b0 + r) * TT + 0) * CC + c4 * 4);
        half4 hv = {(_Float16)xv.x, (_Float16)xv.y, (_Float16)xv.z, (_Float16)xv.w};
        *(half4*)&xs[0][r][c4 * 4] = hv;
    }

    float c_st[4] = {0.f, 0.f, 0.f, 0.f};
    float P[4]    = {0.f, 0.f, 0.f, 0.f};
    float hprev[4] = {0.f, 0.f, 0.f, 0.f};   // h_{t-1} after activations
    float hpp[4]   = {0.f, 0.f, 0.f, 0.f};   // h_{t-2}
    float mreg = -INFINITY, Sreg = 0.f;
    __syncthreads();

    for (int t = 0; t < TT; ++t) {
        const int hb = (t + 1) & 1;    // buffer holding h_{t-1}
        const float s_t = ws[t];

        // prefetch next x (global)
        float4 xv;
        const int xr = tid >> 3, xc4 = tid & 7;
        if (tid < 128 && t + 1 < TT)
            xv = *reinterpret_cast<const float4*>(x + ((size_t)(b0 + xr) * TT + (t + 1)) * CC + xc4 * 4);

        // ---- logit for h_{t-1} -> ab2[t&1] ----
        if (t > 0) {
            half4 hh = *(const half4*)&hs[hb][rrow][kc * 4];
            float acc = 0.f;
#pragma unroll
            for (int i = 0; i < 4; ++i) acc = fmaf(aw[i], (float)hh[i], acc);
#pragma unroll
            for (int off = 1; off < 32; off <<= 1) acc += __shfl_xor(acc, off, 64);
            float logit = acc + attb;
            float mn    = fmaxf(mreg, logit);
            float alpha = __expf(mreg - mn);
            float beta  = __expf(logit - mn);
            Sreg = Sreg * alpha + beta;
            mreg = mn;
            if (kc == 0) { ab2[t & 1][0][rrow] = alpha; ab2[t & 1][1][rrow] = beta; }
        }

        // ---- P update with ab of step t-1 (covers h_{t-2}) ----
        if (t >= 2) {
#pragma unroll
            for (int i = 0; i < 4; ++i) {
                const int r_i = q * 4 + i;
                P[i] = fmaf(P[i], ab2[(t - 1) & 1][0][r_i], ab2[(t - 1) & 1][1][r_i] * hpp[i]);
            }
        }

        // ---- gates: C init + 20 MFMA ----
        f32x4 acc0, acc1, acc2, acc3;
        {
            float c0 = fmaf(w32g[0], s_t, biasg[0]);
            float c1 = fmaf(w32g[1], s_t, biasg[1]);
            float c2 = fmaf(w32g[2], s_t, biasg[2]);
            float c3 = fmaf(w32g[3], s_t, biasg[3]);
            acc0 = (f32x4){c0, c0, c0, c0};
            acc1 = (f32x4){c1, c1, c1, c1};
            acc2 = (f32x4){c2, c2, c2, c2};
            acc3 = (f32x4){c3, c3, c3, c3};
        }
#pragma unroll
        for (int kt = 0; kt < 5; ++kt) {
            half8 ah;
            if (kt < 4) ah = *(const half8*)&hs[hb][m][kt * 32 + q * 8];
            else        ah = *(const half8*)&xs[t & 1][m][q * 8];
            acc0 = MFMA16H(ah, Bf[0][kt], acc0);
            acc1 = MFMA16H(ah, Bf[1][kt], acc1);
            acc2 = MFMA16H(ah, Bf[2][kt], acc2);
            acc3 = MFMA16H(ah, Bf[3][kt], acc3);
        }

        // ---- stage x_{t+1} ----
        if (tid < 128 && t + 1 < TT) {
            half4 hv = {(_Float16)xv.x, (_Float16)xv.y, (_Float16)xv.z, (_Float16)xv.w};
            *(half4*)&xs[(t + 1) & 1][xr][xc4 * 4] = hv;
        }

        // ---- activations + state update (rows q*4+i, column jcol) ----
#pragma unroll
        for (int i = 0; i < 4; ++i) {
            float ig = fsig(acc0[i]);
            float fg = fsig(acc1[i]);
            float gg = ftanh(acc2[i]);
            float og = fsig(acc3[i]);
            c_st[i] = fmaf(fg, c_st[i], ig * gg);
            float hv = og * ftanh(c_st[i]);
            hpp[i]   = hprev[i];
            hprev[i] = hv;
            hs[t & 1][q * 4 + i][jcol] = (_Float16)hv;
        }

        __syncthreads();   // single barrier: h_t, x_{t+1}, ab2[t&1] visible
    }

    // ---- epilogue ----
    // pending 1: ab2[1] (from t=511's logit, covers h_510) with hpp = h_510
#pragma unroll
    for (int i = 0; i < 4; ++i) {
        const int r_i = q * 4 + i;
        P[i] = fmaf(P[i], ab2[1][0][r_i], ab2[1][1][r_i] * hpp[i]);
    }
    // pending 2: logit for h_511 (in hs[1])
    {
        half4 hh = *(const half4*)&hs[1][rrow][kc * 4];
        float acc = 0.f;
#pragma unroll
        for (int i = 0; i < 4; ++i) acc = fmaf(aw[i], (float)hh[i], acc);
#pragma unroll
        for (int off = 1; off < 32; off <<= 1) acc += __shfl_xor(acc, off, 64);
        float logit = acc + attb;
        float mn    = fmaxf(mreg, logit);
        float alpha = __expf(mreg - mn);
        float beta  = __expf(logit - mn);
        Sreg = Sreg * alpha + beta;
        if (kc == 0) { ab2[0][0][rrow] = alpha; ab2[0][1][rrow] = beta; Sf[rrow] = Sreg; }
    }
    __syncthreads();
    float* sc = (float*)&hs[0][0][0];   // reuse as [16][132] fp32 scratch (8448 B < 8704 B)
#pragma unroll
    for (int i = 0; i < 4; ++i) {
        const int r_i = q * 4 + i;
        float Pv = fmaf(P[i], ab2[0][0][r_i], ab2[0][1][r_i] * hprev[i]);
        sc[r_i * 132 + jcol] = (Pv / Sf[r_i]) * fcwj;
    }
    __syncthreads();
    {
        float acc2 = 0.f;
#pragma unroll
        for (int i = 0; i < 4; ++i) acc2 += sc[rrow * 132 + kc * 4 + i];
#pragma unroll
        for (int off = 1; off < 32; off <<= 1) acc2 += __shfl_xor(acc2, off, 64);
        if (kc == 0) out[b0 + rrow] = acc2 + fc_b[0];
    }
}

// ---------------------------------------------------------------------------
extern "C" void kernel_launch(void* const* d_in, const int* in_sizes, int n_in,
                              void* d_out, int out_size, void* d_ws, size_t ws_size,
                              hipStream_t stream) {
    const float* x      = (const float*)d_in[0];
    const float* w_ih   = (const float*)d_in[1];
    const float* u_ih   = (const float*)d_in[2];
    const float* w_hh   = (const float*)d_in[3];
    const float* u_hh   = (const float*)d_in[4];
    const float* b_ih   = (const float*)d_in[5];
    const float* b_hh   = (const float*)d_in[6];
    const float* attn_w = (const float*)d_in[7];
    const float* attn_b = (const float*)d_in[8];
    const float* fc_w   = (const float*)d_in[9];
    const float* u_fc   = (const float*)d_in[10];
    const float* fc_b   = (const float*)d_in[11];
    float* ws  = (float*)d_ws;
    float* out = (float*)d_out;

    std_kernel<<<TT, 256, 0, stream>>>(x, ws);
    sigma_kernel<<<1, 512, 0, stream>>>(w_ih, u_ih, w_hh, u_hh, fc_w, u_fc, ws);
    lstm_mfma<<<BB / 16, 512, 0, stream>>>(x, w_ih, w_hh, b_ih, b_hh,
                                           attn_w, attn_b, fc_w, fc_b, ws, out);
}